// Round 6
// baseline (68.747 us; speedup 1.0000x reference)
//
#include <hip/hip_runtime.h>

typedef unsigned int uint32;
typedef __attribute__((ext_vector_type(2))) float f32x2;

#define QT 16        // queries per thread
#define THREADS 256
#define STAGE_PAIRS 256  // pairs per LDS stage round: 256*32B = 8 KB

// Prep:
//  Qp[i]  = (x, y, z, |p|^2)                       (query-side load, float4)
//  Spairs = per point-pair g: 8 floats
//           [-2x0,-2x1, -2y0,-2y1, -2z0,-2z1, w0,w1]  (scan-side, packed-fp32)
//  bits   = +inf
__global__ __launch_bounds__(THREADS) void cd_prep(
    const float* __restrict__ A, int n, const float* __restrict__ B, int m,
    float4* __restrict__ Qa, float4* __restrict__ Qb,
    float* __restrict__ SpA, float* __restrict__ SpB,
    uint32* __restrict__ bits)
{
    const int i = blockIdx.x * THREADS + threadIdx.x;
    const int total = n + m;
    if (i < total) bits[i] = 0x7F800000u;  // +inf

    if (i < n) {
        float x = A[3 * i], y = A[3 * i + 1], z = A[3 * i + 2];
        float w = fmaf(x, x, fmaf(y, y, z * z));
        Qa[i] = make_float4(x, y, z, w);
        float* s = SpA + (size_t)(i >> 1) * 8 + (i & 1);
        s[0] = -2.f * x; s[2] = -2.f * y; s[4] = -2.f * z; s[6] = w;
    } else if ((n & 1) && i == n) {  // pad slot (sentinel)
        float* s = SpA + (size_t)(i >> 1) * 8 + (i & 1);
        s[0] = 0.f; s[2] = 0.f; s[4] = 0.f; s[6] = 1e30f;
    }
    if (i < m) {
        float x = B[3 * i], y = B[3 * i + 1], z = B[3 * i + 2];
        float w = fmaf(x, x, fmaf(y, y, z * z));
        Qb[i] = make_float4(x, y, z, w);
        float* s = SpB + (size_t)(i >> 1) * 8 + (i & 1);
        s[0] = -2.f * x; s[2] = -2.f * y; s[4] = -2.f * z; s[6] = w;
    } else if ((m & 1) && i == m) {
        float* s = SpB + (size_t)(i >> 1) * 8 + (i & 1);
        s[0] = 0.f; s[2] = 0.f; s[4] = 0.f; s[6] = 1e30f;
    }
}

// Both directions in one launch (blockIdx.z). 16 queries/thread (duplicated
// into f32x2 pairs); scanned pairs staged in LDS, read as wave-uniform
// ds_read_b128 broadcasts, consumed by v_pk_fma_f32 (2 points/inst) +
// v_min3_f32. Tracks min_j(b^2 - 2 a.b); a^2 added at the tail; result
// combined via atomicMin on float bits (deterministic: min is order-free).
__global__ __launch_bounds__(THREADS, 3) void cd_pass(
    const float4* __restrict__ Qa, int n, const float* __restrict__ SpA, int npairs,
    const float4* __restrict__ Qb, int m, const float* __restrict__ SpB, int mpairs,
    int split, uint32* __restrict__ bits)
{
    __shared__ float4 sb[2 * STAGE_PAIRS];

    const float4* Q; const float4* S4; uint32* out; int nq, nsp;
    if (blockIdx.z == 0) { Q = Qa; nq = n; S4 = (const float4*)SpB; nsp = mpairs; out = bits; }
    else                 { Q = Qb; nq = m; S4 = (const float4*)SpA; nsp = npairs; out = bits + n; }

    const int nth = gridDim.x * THREADS;
    const int t = blockIdx.x * THREADS + threadIdx.x;

    f32x2 qx2[QT], qy2[QT], qz2[QT];
    float a2[QT], mn[QT];
#pragma unroll
    for (int k = 0; k < QT; ++k) {
        const int i = t + k * nth;
        float4 q = (i < nq) ? Q[i] : make_float4(0.f, 0.f, 0.f, 0.f);
        qx2[k] = (f32x2){q.x, q.x};
        qy2[k] = (f32x2){q.y, q.y};
        qz2[k] = (f32x2){q.z, q.z};
        a2[k] = q.w;
        mn[k] = __builtin_inff();
    }

    const int chunk = (nsp + split - 1) / split;
    const int j0 = blockIdx.y * chunk;
    const int j1 = min(j0 + chunk, nsp);

    for (int base = j0; base < j1; base += STAGE_PAIRS) {
        const int cnt = min(STAGE_PAIRS, j1 - base);  // pairs this round
        __syncthreads();
        for (int u = threadIdx.x; u < 2 * cnt; u += THREADS)
            sb[u] = S4[2 * (size_t)base + u];
        __syncthreads();

        auto body = [&](int g) {
            const float4 u0 = sb[2 * g + 0];  // [-2x0,-2x1,-2y0,-2y1]
            const float4 u1 = sb[2 * g + 1];  // [-2z0,-2z1,  w0,  w1]
            const f32x2 xx = (f32x2){u0.x, u0.y};
            const f32x2 yy = (f32x2){u0.z, u0.w};
            const f32x2 zz = (f32x2){u1.x, u1.y};
            const f32x2 ww = (f32x2){u1.z, u1.w};
#pragma unroll
            for (int k = 0; k < QT; ++k) {
                f32x2 tt;
                asm("v_pk_fma_f32 %0, %1, %2, %3" : "=v"(tt) : "v"(zz), "v"(qz2[k]), "v"(ww));
                asm("v_pk_fma_f32 %0, %1, %2, %0" : "+v"(tt) : "v"(yy), "v"(qy2[k]));
                asm("v_pk_fma_f32 %0, %1, %2, %0" : "+v"(tt) : "v"(xx), "v"(qx2[k]));
                mn[k] = fminf(fminf(mn[k], tt.x), tt.y);  // v_min3_f32
            }
        };

        int g = 0;
        for (; g + 4 <= cnt; g += 4) { body(g); body(g + 1); body(g + 2); body(g + 3); }
        for (; g < cnt; ++g) body(g);
    }

#pragma unroll
    for (int k = 0; k < QT; ++k) {
        const int i = t + k * nth;
        if (i < nq) {
            const float sq = fmaxf(a2[k] + mn[k], 0.f);
            atomicMin(&out[i], __float_as_uint(sq));
        }
    }
}

__global__ __launch_bounds__(1024) void cd_reduce(
    const uint32* __restrict__ bits, int count, float* __restrict__ out)
{
    __shared__ double sw[16];
    double s = 0.0;
    for (int i = threadIdx.x; i < count; i += 1024)
        s += (double)sqrtf(__uint_as_float(bits[i]));
#pragma unroll
    for (int off = 32; off > 0; off >>= 1) s += __shfl_down(s, off, 64);
    const int lane = threadIdx.x & 63, wid = threadIdx.x >> 6;
    if (lane == 0) sw[wid] = s;
    __syncthreads();
    if (threadIdx.x == 0) {
        double tot = 0.0;
        for (int w = 0; w < 16; ++w) tot += sw[w];
        out[0] = (float)(tot / (double)count);
    }
}

extern "C" void kernel_launch(void* const* d_in, const int* in_sizes, int n_in,
                              void* d_out, int out_size, void* d_ws, size_t ws_size,
                              hipStream_t stream) {
    const float* a = (const float*)d_in[0];
    const float* b = (const float*)d_in[1];
    const int n = in_sizes[0] / 3;
    const int m = in_sizes[1] / 3;
    const int total = n + m;
    float* out = (float*)d_out;

    const int npairs = (n + 1) / 2;
    const int mpairs = (m + 1) / 2;

    // ws: Qa[n] f4 | Qb[m] f4 | SpA[npairs*8] f | SpB[mpairs*8] f | bits[total]
    char* wp = (char*)d_ws;
    float4* Qa = (float4*)wp;        wp += (size_t)n * 16;
    float4* Qb = (float4*)wp;        wp += (size_t)m * 16;
    float* SpA = (float*)wp;         wp += (size_t)npairs * 32;
    float* SpB = (float*)wp;         wp += (size_t)mpairs * 32;
    uint32* bits = (uint32*)wp;

    cd_prep<<<(total + THREADS - 1) / THREADS, THREADS, 0, stream>>>(
        a, n, b, m, Qa, Qb, SpA, SpB, bits);

    const int mx = max(n, m);
    const int bx = (mx + QT * THREADS - 1) / (QT * THREADS);
    int split = max(1, (3 * 256) / (bx * 2));  // target 3 blocks/CU exactly
    dim3 grid(bx, split, 2);
    cd_pass<<<grid, THREADS, 0, stream>>>(Qa, n, SpA, npairs,
                                          Qb, m, SpB, mpairs, split, bits);

    cd_reduce<<<1, 1024, 0, stream>>>(bits, total, out);
}